// Round 8
// baseline (2247.422 us; speedup 1.0000x reference)
//
#include <hip/hip_runtime.h>
#include <stdint.h>

#define DI __device__ __forceinline__

typedef _Float16 f16x8 __attribute__((ext_vector_type(8)));
typedef float f32x4 __attribute__((ext_vector_type(4)));
typedef unsigned long long u64;
typedef unsigned short u16;

// ---- problem constants ----
constexpr int kB = 4;
constexpr int kN = 65536;
constexpr int kG = 512;   // NUM_GROUP
constexpr int kM = 64;    // GROUP_SIZE
constexpr int kE = 60;    // EMB
constexpr int GRD = 16;   // unified grid resolution (FPS chunks == cells)
constexpr int NCELL = GRD * GRD * GRD;   // 4096
constexpr float CW = 1.0f / 16.0f;       // exactly representable

constexpr int TPB = 512;    // threads per block (8 waves)
constexpr int NWORK = 252;  // worker blocks
constexpr int NBLK = 256;   // 4 fps + 252 workers, 1 block/CU -> all co-resident

// ---- workspace layout (bytes) ----
// cline per (b,it): 128B line, 3 tagged words: (coord_bits<<32)|(it+1). 1 writer.
constexpr size_t OFF_CLINE  = 0;
constexpr size_t OFF_CCNT   = OFF_CLINE + (size_t)kB * kG * 128;
constexpr size_t OFF_GS     = OFF_CCNT + (size_t)kB * NCELL * 4;
constexpr size_t ZERO_BYTES = OFF_GS + 64;
constexpr size_t OFF_CSTART = (ZERO_BYTES + 255) & ~(size_t)255;   // kB*(NCELL+1) u32
constexpr size_t OFF_CUR    = OFF_CSTART + (size_t)kB * (NCELL + 1) * 4;
constexpr size_t OFF_DD     = ((OFF_CUR + (size_t)kB * NCELL * 4) + 255) & ~(size_t)255;
constexpr size_t OFF_SW1    = (OFF_DD + (size_t)kB * kN * 4 + 255) & ~(size_t)255;
constexpr size_t OFF_SW2    = OFF_SW1 + 2048 * 2;
constexpr size_t OFF_SW3    = OFF_SW2 + 8192 * 2;
constexpr size_t OFF_SW4    = OFF_SW3 + 32768 * 2;
constexpr size_t OFF_WPT    = OFF_SW4 + 131072 * 2;
constexpr size_t OFF_SORT   = ((OFF_WPT + 60 * 512 * 4) + 255) & ~(size_t)255; // kB*kN float4

DI int cellof(float x) {
  int c = (int)(x * (float)GRD);
  return min(GRD - 1, max(0, c));
}
DI unsigned orderable(float f) {
  unsigned u = __float_as_uint(f);
  return (u & 0x80000000u) ? ~u : (u | 0x80000000u);
}

// =====================  zero the sync/count region  =====================
__global__ void k_zero(uint32_t* p, int nwords) {
  int i = blockIdx.x * blockDim.x + threadIdx.x;
  int st = gridDim.x * blockDim.x;
  for (; i < nwords; i += st) p[i] = 0u;
}

// =====================  weight prep: B-fragment swizzle (f16) + WpT  =====================
DI void swz(const float* __restrict__ W, _Float16* __restrict__ sw,
            int total, int nks, int Kreal, int N, int i0, int st) {
  for (int i = i0; i < total; i += st) {
    int j = i & 7, lane = (i >> 3) & 63, rest = i >> 9;
    int ks = rest % nks, nt = rest / nks;
    int k = ks * 32 + ((lane >> 4) << 3) + j;
    int n = nt * 16 + (lane & 15);
    sw[i] = (_Float16)((k < Kreal) ? W[k * N + n] : 0.f);
  }
}

__global__ void k_prep(const float* __restrict__ W1, const float* __restrict__ W2,
                       const float* __restrict__ W3, const float* __restrict__ W4,
                       const float* __restrict__ Wp,
                       _Float16* __restrict__ sw1, _Float16* __restrict__ sw2,
                       _Float16* __restrict__ sw3, _Float16* __restrict__ sw4,
                       float* __restrict__ wpt) {
  int i0 = blockIdx.x * blockDim.x + threadIdx.x;
  int st = gridDim.x * blockDim.x;
  swz(W1, sw1, 2048, 1, 6, 64, i0, st);
  swz(W2, sw2, 8192, 2, 64, 128, i0, st);
  swz(W3, sw3, 32768, 4, 128, 256, i0, st);
  swz(W4, sw4, 131072, 8, 256, 512, i0, st);
  for (int i = i0; i < 60 * 512; i += st) { int n = i >> 9, k = i & 511; wpt[i] = Wp[k * 60 + n]; }
}

// =====================  device-wide phase barrier (co-resident workers)  =====================
DI void gbar(uint32_t* ctr, unsigned target) {
  __syncthreads();
  if (threadIdx.x == 0) {
    __hip_atomic_fetch_add(ctr, 1u, __ATOMIC_ACQ_REL, __HIP_MEMORY_SCOPE_AGENT);
    long bail = 0;
    while (__hip_atomic_load(ctr, __ATOMIC_ACQUIRE, __HIP_MEMORY_SCOPE_AGENT) < target) {
      __builtin_amdgcn_s_sleep(32);
      if (++bail > 100000000L) break;
    }
  }
  __syncthreads();
}

// =====================  FPS: refine two cells with one load volley  ======
// 4-lane group; exact math chain identical to reference. Writes ckey for both.
DI void refine_pair(int c0, int c1, const float4* __restrict__ SP,
                    float* __restrict__ DD, const uint32_t* __restrict__ lcs,
                    float cx, float cy, float cz, int lig, bool first,
                    u64* __restrict__ ckey) {
  const int a0 = (int)lcs[c0], a1 = (int)lcs[c0 + 1];
  const int baseA = a0 + lig;
  float4 pA[8]; float dA[8];
#pragma unroll
  for (int j = 0; j < 8; ++j) {
    int p = baseA + 4 * j;
    int pc = max(min(p, a1 - 1), 0);
    pA[j] = SP[pc];
    dA[j] = first ? 1e10f : DD[pc];
  }
  int b0 = 0, b1 = 0, baseB = 0;
  float4 pB[8]; float dB[8];
  if (c1 >= 0) {
    b0 = (int)lcs[c1]; b1 = (int)lcs[c1 + 1];
    baseB = b0 + lig;
#pragma unroll
    for (int j = 0; j < 8; ++j) {
      int p = baseB + 4 * j;
      int pc = max(min(p, b1 - 1), 0);
      pB[j] = SP[pc];
      dB[j] = first ? 1e10f : DD[pc];
    }
  }
  u64 keyA = 0ull;
#pragma unroll
  for (int j = 0; j < 8; ++j) {
    int p = baseA + 4 * j;
    if (p < a1) {
      float dx = __fsub_rn(pA[j].x, cx);
      float dy = __fsub_rn(pA[j].y, cy);
      float dz = __fsub_rn(pA[j].z, cz);
      float d = __fadd_rn(__fadd_rn(__fmul_rn(dx, dx), __fmul_rn(dy, dy)), __fmul_rn(dz, dz));
      float nd = fminf(dA[j], d);
      DD[p] = nd;
      u64 k = ((u64)__float_as_uint(nd) << 32) |
              (u64)(0xFFFFFFFFu - (unsigned)__float_as_uint(pA[j].w));
      keyA = (k > keyA) ? k : keyA;
    }
  }
  for (int p = baseA + 32; p < a1; p += 4) {   // rare: cells with >32 points
    float4 pp = SP[p];
    float od = first ? 1e10f : DD[p];
    float dx = __fsub_rn(pp.x, cx);
    float dy = __fsub_rn(pp.y, cy);
    float dz = __fsub_rn(pp.z, cz);
    float d = __fadd_rn(__fadd_rn(__fmul_rn(dx, dx), __fmul_rn(dy, dy)), __fmul_rn(dz, dz));
    float nd = fminf(od, d);
    DD[p] = nd;
    u64 k = ((u64)__float_as_uint(nd) << 32) |
            (u64)(0xFFFFFFFFu - (unsigned)__float_as_uint(pp.w));
    keyA = (k > keyA) ? k : keyA;
  }
  u64 o = __shfl_xor(keyA, 1); keyA = (o > keyA) ? o : keyA;
  o = __shfl_xor(keyA, 2); keyA = (o > keyA) ? o : keyA;
  if (lig == 0) ckey[c0] = keyA;
  if (c1 >= 0) {
    u64 keyB = 0ull;
#pragma unroll
    for (int j = 0; j < 8; ++j) {
      int p = baseB + 4 * j;
      if (p < b1) {
        float dx = __fsub_rn(pB[j].x, cx);
        float dy = __fsub_rn(pB[j].y, cy);
        float dz = __fsub_rn(pB[j].z, cz);
        float d = __fadd_rn(__fadd_rn(__fmul_rn(dx, dx), __fmul_rn(dy, dy)), __fmul_rn(dz, dz));
        float nd = fminf(dB[j], d);
        DD[p] = nd;
        u64 k = ((u64)__float_as_uint(nd) << 32) |
                (u64)(0xFFFFFFFFu - (unsigned)__float_as_uint(pB[j].w));
        keyB = (k > keyB) ? k : keyB;
      }
    }
    for (int p = baseB + 32; p < b1; p += 4) {
      float4 pp = SP[p];
      float od = first ? 1e10f : DD[p];
      float dx = __fsub_rn(pp.x, cx);
      float dy = __fsub_rn(pp.y, cy);
      float dz = __fsub_rn(pp.z, cz);
      float d = __fadd_rn(__fadd_rn(__fmul_rn(dx, dx), __fmul_rn(dy, dy)), __fmul_rn(dz, dz));
      float nd = fminf(od, d);
      DD[p] = nd;
      u64 k = ((u64)__float_as_uint(nd) << 32) |
              (u64)(0xFFFFFFFFu - (unsigned)__float_as_uint(pp.w));
      keyB = (k > keyB) ? k : keyB;
    }
    o = __shfl_xor(keyB, 1); keyB = (o > keyB) ? o : keyB;
    o = __shfl_xor(keyB, 2); keyB = (o > keyB) ? o : keyB;
    if (lig == 0) ckey[c1] = keyB;
  }
}

// =====================  FPS: one 512-thread block per batch  ===========
// Static owner map: group g (0..127) owns 32 cells at (gx+4ix, gy+4iy, gz+8iz).
// Per round (2 barriers): fused {bound-test -> pair-refine -> owned-max scan}
// -> barrier -> {final reduce + coord gather + publish} -> barrier.
// LDS: ckey u64[4096] @0 (32KB) | lcs u32[4097] @32768 | warr u64[8] @49408 | wbuf @49472
DI void fps_block(const float* __restrict__ xyz, float* __restrict__ outC,
                  u64* __restrict__ cline, uint32_t* __restrict__ gs,
                  const float4* __restrict__ sorted_g,
                  const uint32_t* __restrict__ cstart_g,
                  float* __restrict__ dd_g, int b, char* smem) {
  __builtin_amdgcn_s_setprio(3);
  const int tid = threadIdx.x;
  const int wv = tid >> 6, lane = tid & 63;
  const int grp = tid >> 2, lig = tid & 3;     // 128 groups x 4 lanes
  const int gx = grp & 3, gy = (grp >> 2) & 3, gz = grp >> 4;
  const float* X = xyz + (size_t)b * kN * 3;
  const float4* SP = sorted_g + (size_t)b * kN;
  float* DD = dd_g + (size_t)b * kN;
  u64* cl = cline + (size_t)b * kG * 16;

  u64* ckey = (u64*)smem;
  uint32_t* lcs = (uint32_t*)(smem + 32768);
  u64* warr = (u64*)(smem + 49408);
  float4* wbuf = (float4*)(smem + 49472);

  float cx = X[0], cy = X[1], cz = X[2];
  if (tid == 0) {
    u64 tg = 1u;  // tag = it+1 for it=0
    __hip_atomic_store(cl + 0, ((u64)__float_as_uint(cx) << 32) | tg, __ATOMIC_RELAXED, __HIP_MEMORY_SCOPE_AGENT);
    __hip_atomic_store(cl + 1, ((u64)__float_as_uint(cy) << 32) | tg, __ATOMIC_RELAXED, __HIP_MEMORY_SCOPE_AGENT);
    __hip_atomic_store(cl + 2, ((u64)__float_as_uint(cz) << 32) | tg, __ATOMIC_RELAXED, __HIP_MEMORY_SCOPE_AGENT);
    outC[(size_t)b * kG * 3 + 0] = cx;
    outC[(size_t)b * kG * 3 + 1] = cy;
    outC[(size_t)b * kG * 3 + 2] = cz;
    long bail = 0;   // wait for workers' grid build (acquire)
    while (__hip_atomic_load(gs + 2, __ATOMIC_ACQUIRE, __HIP_MEMORY_SCOPE_AGENT) < NWORK) {
      __builtin_amdgcn_s_sleep(16);
      if (++bail > 200000000L) break;
    }
  }
  __syncthreads();
  for (int i = tid; i <= NCELL; i += TPB) lcs[i] = cstart_g[(size_t)b * (NCELL + 1) + i];
  __syncthreads();

  for (int it = 1; it < kG; ++it) {
    const bool first = (it == 1);
    // ---- fused: bound-test owned cells -> refine pairs -> owned-key max ----
    unsigned mask;
    if (first) {
      mask = 0xFFFFFFFFu;
    } else {
      unsigned pm = 0;
#pragma unroll
      for (int j = 0; j < 8; ++j) {
        int m = lig * 8 + j;
        int cxi = gx + 4 * (m & 3);
        int cyi = gy + 4 * ((m >> 2) & 3);
        int czi = gz + 8 * (m >> 4);
        int c = (czi * GRD + cyi) * GRD + cxi;
        float x0 = (float)cxi * CW;
        float y0 = (float)cyi * CW;
        float z0 = (float)czi * CW;
        float dx = fmaxf(fmaxf(x0 - cx, cx - (x0 + CW)), 0.f);
        float dy = fmaxf(fmaxf(y0 - cy, cy - (y0 + CW)), 0.f);
        float dz = fmaxf(fmaxf(z0 - cz, cz - (z0 + CW)), 0.f);
        float lb = dx * dx + dy * dy + dz * dz;
        float ub = __uint_as_float(((const uint32_t*)ckey)[2 * c + 1]);
        if (!(lb * 0.999f > ub)) pm |= 1u << m;   // conservative skip
      }
      pm |= __shfl_xor(pm, 1);
      pm |= __shfl_xor(pm, 2);
      mask = pm;
    }
    while (mask) {
      int m0 = __ffs(mask) - 1; mask &= mask - 1;
      int m1 = -1;
      if (mask) { m1 = __ffs(mask) - 1; mask &= mask - 1; }
      int c0 = ((gz + 8 * (m0 >> 4)) * GRD + (gy + 4 * ((m0 >> 2) & 3))) * GRD + (gx + 4 * (m0 & 3));
      int c1 = (m1 >= 0)
             ? ((gz + 8 * (m1 >> 4)) * GRD + (gy + 4 * ((m1 >> 2) & 3))) * GRD + (gx + 4 * (m1 & 3))
             : -1;
      refine_pair(c0, c1, SP, DD, lcs, cx, cy, cz, lig, first, ckey);
    }
    // owned-key max (covers all 4096 cells across 128 groups)
    u64 gkey = 0ull;
#pragma unroll
    for (int j = 0; j < 8; ++j) {
      int m = lig * 8 + j;
      int c = ((gz + 8 * (m >> 4)) * GRD + (gy + 4 * ((m >> 2) & 3))) * GRD + (gx + 4 * (m & 3));
      u64 k = ckey[c];
      gkey = (k > gkey) ? k : gkey;
    }
#pragma unroll
    for (int off = 1; off < 64; off <<= 1) {
      u64 o = __shfl_xor(gkey, off);
      gkey = (o > gkey) ? o : gkey;
    }
    if (lane == 0) warr[wv] = gkey;
    __syncthreads();
    // ---- final reduce + coord gather + buffered publish ----
    if (tid == 0) {
      u64 k = warr[0];
#pragma unroll
      for (int i = 1; i < 8; ++i) k = (warr[i] > k) ? warr[i] : k;
      unsigned wi = 0xFFFFFFFFu - (unsigned)(k & 0xFFFFFFFFu);
      wbuf[it & 3] = make_float4(X[3 * wi], X[3 * wi + 1], X[3 * wi + 2], 0.f);
    }
    __syncthreads();
    float4 wc = wbuf[it & 3];
    cx = wc.x; cy = wc.y; cz = wc.z;
    // batched fire-and-forget publish every 4 rounds (amortizes store drain)
    if ((it & 3) == 3 || it == kG - 1) {
      int k0 = it & ~3;
      if (tid <= (it & 3) && (k0 + tid) >= 1) {
        int itp = k0 + tid;
        float4 w = wbuf[tid];
        u64 tg = (unsigned)(itp + 1);
        u64* e = cl + (size_t)itp * 16;
        __hip_atomic_store(e + 0, ((u64)__float_as_uint(w.x) << 32) | tg, __ATOMIC_RELAXED, __HIP_MEMORY_SCOPE_AGENT);
        __hip_atomic_store(e + 1, ((u64)__float_as_uint(w.y) << 32) | tg, __ATOMIC_RELAXED, __HIP_MEMORY_SCOPE_AGENT);
        __hip_atomic_store(e + 2, ((u64)__float_as_uint(w.z) << 32) | tg, __ATOMIC_RELAXED, __HIP_MEMORY_SCOPE_AGENT);
        outC[((size_t)b * kG + itp) * 3 + 0] = w.x;
        outC[((size_t)b * kG + itp) * 3 + 1] = w.y;
        outC[((size_t)b * kG + itp) * 3 + 2] = w.z;
      }
    }
  }
}

// =====================  bitonic sort (shared, 512 threads)  =====================
DI void bitonic(u64* a, int n, int tid) {
  for (int k = 2; k <= n; k <<= 1)
    for (int j = k >> 1; j > 0; j >>= 1) {
      __syncthreads();
      for (int i = tid; i < n; i += TPB) {
        int ix = i ^ j;
        if (ix > i) {
          u64 x = a[i], y = a[ix];
          bool up = ((i & k) == 0);
          if ((x > y) == up) { a[i] = y; a[ix] = x; }
        }
      }
    }
  __syncthreads();
}

// =====================  MLP layers (f16 MFMA; waves 0-3 only)  =====================
template <int Kdim, int Ndim, int SIN, int SOUT>
DI void mfma_layer(const _Float16* __restrict__ Xin, _Float16* __restrict__ Xout,
                   const _Float16* __restrict__ Wsw, const float* __restrict__ bias,
                   int wave, int lane) {
  constexpr int NKS = Kdim / 32;
  constexpr int NTW = Ndim / 64;
  constexpr int CH = (NTW < 4) ? NTW : 4;
  const int quad = lane >> 4, l16 = lane & 15;
  for (int c0 = 0; c0 < NTW; c0 += CH) {
    f32x4 acc[CH][4];
#pragma unroll
    for (int nt = 0; nt < CH; ++nt) {
      float bv = bias[wave * (Ndim / 4) + (c0 + nt) * 16 + l16];
#pragma unroll
      for (int m = 0; m < 4; ++m) acc[nt][m] = {bv, bv, bv, bv};
    }
#pragma unroll
    for (int ks = 0; ks < NKS; ++ks) {
      f16x8 af[4];
#pragma unroll
      for (int m = 0; m < 4; ++m)
        af[m] = *(const f16x8*)(Xin + (m * 16 + l16) * SIN + ks * 32 + quad * 8);
#pragma unroll
      for (int nt = 0; nt < CH; ++nt) {
        int ntg = wave * NTW + c0 + nt;
        f16x8 bf = *(const f16x8*)(Wsw + ((size_t)(ntg * NKS + ks) * 64 + lane) * 8);
#pragma unroll
        for (int m = 0; m < 4; ++m)
          acc[nt][m] = __builtin_amdgcn_mfma_f32_16x16x32_f16(af[m], bf, acc[nt][m], 0, 0, 0);
      }
    }
#pragma unroll
    for (int nt = 0; nt < CH; ++nt) {
      int col = wave * (Ndim / 4) + (c0 + nt) * 16 + l16;
#pragma unroll
      for (int m = 0; m < 4; ++m)
#pragma unroll
        for (int r = 0; r < 4; ++r) {
          int row = m * 16 + quad * 4 + r;
          Xout[row * SOUT + col] = (_Float16)fmaxf(acc[nt][m][r], 0.f);
        }
    }
  }
}

DI void mfma_layer4(const _Float16* __restrict__ Xin, const _Float16* __restrict__ Wsw,
                    const float* __restrict__ bias, float* __restrict__ maxv,
                    int wave, int lane) {
  constexpr int SIN = 264, NKS = 8, NTW = 8, CH = 4;
  const int quad = lane >> 4, l16 = lane & 15;
  for (int c0 = 0; c0 < NTW; c0 += CH) {
    f32x4 acc[CH][4];
#pragma unroll
    for (int nt = 0; nt < CH; ++nt) {
      float bv = bias[wave * 128 + (c0 + nt) * 16 + l16];
#pragma unroll
      for (int m = 0; m < 4; ++m) acc[nt][m] = {bv, bv, bv, bv};
    }
#pragma unroll
    for (int ks = 0; ks < NKS; ++ks) {
      f16x8 af[4];
#pragma unroll
      for (int m = 0; m < 4; ++m)
        af[m] = *(const f16x8*)(Xin + (m * 16 + l16) * SIN + ks * 32 + quad * 8);
#pragma unroll
      for (int nt = 0; nt < CH; ++nt) {
        int ntg = wave * NTW + c0 + nt;
        f16x8 bf = *(const f16x8*)(Wsw + ((size_t)(ntg * NKS + ks) * 64 + lane) * 8);
#pragma unroll
        for (int m = 0; m < 4; ++m)
          acc[nt][m] = __builtin_amdgcn_mfma_f32_16x16x32_f16(af[m], bf, acc[nt][m], 0, 0, 0);
      }
    }
#pragma unroll
    for (int nt = 0; nt < CH; ++nt) {
      float mx = 0.f;  // relu folded into max
#pragma unroll
      for (int m = 0; m < 4; ++m)
#pragma unroll
        for (int r = 0; r < 4; ++r) mx = fmaxf(mx, acc[nt][m][r]);
      mx = fmaxf(mx, __shfl_xor(mx, 16, 64));
      mx = fmaxf(mx, __shfl_xor(mx, 32, 64));
      if (quad == 0) maxv[wave * 128 + (c0 + nt) * 16 + l16] = mx;
    }
  }
}

// =====================  fused kernel  =====================
__global__ __launch_bounds__(TPB, 2) void k_fused(
    const float* __restrict__ xyz, const float* __restrict__ color,
    float* __restrict__ outC, float* __restrict__ outE,
    u64* __restrict__ cline, uint32_t* __restrict__ ccnt,
    uint32_t* __restrict__ cstart, uint32_t* __restrict__ cur,
    float4* __restrict__ sorted, float* __restrict__ dd_g,
    uint32_t* __restrict__ gs,
    const _Float16* __restrict__ sw1, const _Float16* __restrict__ sw2,
    const _Float16* __restrict__ sw3, const _Float16* __restrict__ sw4,
    const float* __restrict__ wpt,
    const float* __restrict__ b1, const float* __restrict__ b2,
    const float* __restrict__ b3, const float* __restrict__ b4,
    const float* __restrict__ bp) {
  __shared__ __align__(16) char smem[65536];
  const int bi = blockIdx.x;
  if (bi < kB) {  // FPS block for batch bi (own CU: 256 blocks on 256 CUs)
    fps_block(xyz, outC, cline, gs, sorted, cstart, dd_g, bi, smem);
    return;
  }

  // ---------------- worker block ----------------
  const int wj = bi - kB;  // 0..251
  const int tid = threadIdx.x;
  const int wave = tid >> 6, lane = tid & 63;
  __shared__ int nC;
  __shared__ float4 spc;
  __shared__ uint32_t s_part[TPB];
  u64* cand = (u64*)smem;

  // ---- grid build (single 16^3 grid for KNN + FPS) ----
  for (int i = wj * TPB + tid; i < kB * kN; i += NWORK * TPB) {
    int b = i >> 16, p = i & (kN - 1);
    const float* q = xyz + ((size_t)b * kN + p) * 3;
    int cid = (cellof(q[2]) * GRD + cellof(q[1])) * GRD + cellof(q[0]);
    atomicAdd(&ccnt[b * NCELL + cid], 1u);
  }
  gbar(gs + 0, NWORK);
  if (wj < kB) {
    int b = wj;
    const uint32_t* cc = ccnt + (size_t)b * NCELL;
    uint32_t* cs = cstart + (size_t)b * (NCELL + 1);
    uint32_t* cu = cur + (size_t)b * NCELL;
    const int chunk = NCELL / TPB;   // 8
    int c0 = tid * chunk;
    uint32_t s = 0;
    for (int i = 0; i < chunk; ++i) s += cc[c0 + i];
    s_part[tid] = s;
    __syncthreads();
    for (int off = 1; off < TPB; off <<= 1) {
      uint32_t add = (tid >= off) ? s_part[tid - off] : 0u;
      __syncthreads();
      s_part[tid] += add;
      __syncthreads();
    }
    uint32_t run = s_part[tid] - s;
    for (int i = 0; i < chunk; ++i) {
      int c = c0 + i;
      cs[c] = run; cu[c] = run; run += cc[c];
    }
    if (tid == TPB - 1) cs[NCELL] = run;
  }
  gbar(gs + 1, NWORK);
  for (int i = wj * TPB + tid; i < kB * kN; i += NWORK * TPB) {
    int b = i >> 16, p = i & (kN - 1);
    const float* q = xyz + ((size_t)b * kN + p) * 3;
    float x = q[0], y = q[1], z = q[2];
    int cid = (cellof(z) * GRD + cellof(y)) * GRD + cellof(x);
    uint32_t pos = atomicAdd(&cur[b * NCELL + cid], 1u);
    sorted[(size_t)b * kN + pos] = make_float4(x, y, z, __uint_as_float((unsigned)p));
  }
  gbar(gs + 2, NWORK);   // FPS blocks wait on this counter

  // ---- consume groups in production order: job j = it*4 + b ----
  for (int j = wj; j < kB * kG; j += NWORK) {
    const int it = j >> 2, b = j & 3;
    if (tid < 64) {
      const u64* e = cline + ((size_t)b * kG + it) * 16;
      u64 v = 0; long bail = 0;
      for (;;) {
        if (lane < 3)
          v = __hip_atomic_load(e + lane, __ATOMIC_RELAXED, __HIP_MEMORY_SCOPE_AGENT);
        bool ok = (lane >= 3) || ((unsigned)v == (unsigned)(it + 1));
        if (__all(ok)) break;
        __builtin_amdgcn_s_sleep(8);
        if (++bail > 100000000L) break;
      }
      u64 v0 = __shfl(v, 0), v1 = __shfl(v, 1), v2 = __shfl(v, 2);
      if (tid == 0)
        spc = make_float4(__uint_as_float((unsigned)(v0 >> 32)),
                          __uint_as_float((unsigned)(v1 >> 32)),
                          __uint_as_float((unsigned)(v2 >> 32)), 0.f);
    }
    __syncthreads();
    const float cx = spc.x, cy = spc.y, cz = spc.z;

    // ---- KNN (expanding box + exact re-rank + bitonic) ----
    const float nc = __fadd_rn(__fadd_rn(__fmul_rn(cx, cx), __fmul_rn(cy, cy)), __fmul_rn(cz, cz));
    const float4* SPb = sorted + (size_t)b * kN;
    const uint32_t* CS = cstart + (size_t)b * (NCELL + 1);
    const int ccx = cellof(cx), ccy = cellof(cy), ccz = cellof(cz);
    if (tid == 0) nC = 0;
    __syncthreads();
    int plox = 1, phix = 0, ploy = 1, phiy = 0, ploz = 1, phiz = 0;
    for (int r = 1; r <= GRD; ++r) {
      int lox = max(0, ccx - r), hix = min(GRD - 1, ccx + r);
      int loy = max(0, ccy - r), hiy = min(GRD - 1, ccy + r);
      int loz = max(0, ccz - r), hiz = min(GRD - 1, ccz + r);
      for (int z = loz; z <= hiz; ++z)
        for (int y = loy; y <= hiy; ++y) {
          bool rowPrev = (r > 1) && (z >= ploz && z <= phiz && y >= ploy && y <= phiy);
          for (int s = 0; s < 2; ++s) {
            int xa, xb;
            if (!rowPrev) { if (s) break; xa = lox; xb = hix; }
            else if (s == 0) { xa = lox; xb = plox - 1; }
            else { xa = phix + 1; xb = hix; }
            if (xa > xb) continue;
            int c0 = (z * GRD + y) * GRD + xa;
            int i0 = CS[c0];
            int i1 = CS[(z * GRD + y) * GRD + xb + 1];
            for (int i = i0 + tid; i < i1; i += TPB) {
              float4 pt = SPb[i];
              float npn = __fadd_rn(__fadd_rn(__fmul_rn(pt.x, pt.x), __fmul_rn(pt.y, pt.y)),
                                    __fmul_rn(pt.z, pt.z));
              float dot = __fadd_rn(__fadd_rn(__fmul_rn(cx, pt.x), __fmul_rn(cy, pt.y)),
                                    __fmul_rn(cz, pt.z));
              float sq = __fsub_rn(__fadd_rn(nc, npn), __fmul_rn(2.0f, dot));
              unsigned key = orderable(sq);
              int pos = atomicAdd(&nC, 1);
              if (pos < 8192)
                cand[pos] = ((u64)key << 32) | (unsigned)__float_as_uint(pt.w);
            }
          }
        }
      __syncthreads();
      int n = min(nC, 8192);
      float rc = 1e30f;
      if (lox > 0) rc = fminf(rc, cx - (float)lox * CW);
      if (hix < GRD - 1) rc = fminf(rc, (float)(hix + 1) * CW - cx);
      if (loy > 0) rc = fminf(rc, cy - (float)loy * CW);
      if (hiy < GRD - 1) rc = fminf(rc, (float)(hiy + 1) * CW - cy);
      if (loz > 0) rc = fminf(rc, cz - (float)loz * CW);
      if (hiz < GRD - 1) rc = fminf(rc, (float)(hiz + 1) * CW - cz);
      float r2 = (rc >= 1e29f) ? 3.0e38f : rc * rc * (1.0f - 1e-5f);
      unsigned keyR = orderable(r2);
      bool done = false;
      if (n >= kM) {
        int np2 = 1;
        while (np2 < n) np2 <<= 1;
        for (int i = n + tid; i < np2; i += TPB) cand[i] = ~0ull;
        bitonic(cand, np2, tid);
        unsigned k63 = (unsigned)(cand[kM - 1] >> 32);
        done = (k63 <= keyR);
        if (tid == 0) nC = n;
      }
      __syncthreads();
      if (done) break;
      plox = lox; phix = hix; ploy = loy; phiy = hiy; ploz = loz; phiz = hiz;
    }

    // ---- MLP (waves 0-3 compute; waves 4-7 only hit barriers) ----
    uint32_t pidx = 0;
    if (tid < kM) pidx = (uint32_t)(cand[tid] & 0xFFFFFFFFu);
    __syncthreads();
    _Float16* bufA = (_Float16*)smem;
    _Float16* bufB = (_Float16*)(smem + 17408);
    float* maxv = (float*)smem;
    float* psum = (float*)(smem + 2048);
    if (tid < kM) {
      const float* xp = xyz + ((size_t)b * kN + pidx) * 3;
      const float* cp = color + ((size_t)b * kN + pidx) * 3;
      f16x8 v = {};
      v[0] = (_Float16)__fsub_rn(xp[0], cx);
      v[1] = (_Float16)__fsub_rn(xp[1], cy);
      v[2] = (_Float16)__fsub_rn(xp[2], cz);
      v[3] = (_Float16)cp[0];
      v[4] = (_Float16)cp[1];
      v[5] = (_Float16)cp[2];
      f16x8 zf = {};
      *(f16x8*)(bufA + tid * 40 + 0) = v;
      *(f16x8*)(bufA + tid * 40 + 8) = zf;
      *(f16x8*)(bufA + tid * 40 + 16) = zf;
      *(f16x8*)(bufA + tid * 40 + 24) = zf;
    }
    __syncthreads();
    if (tid < 256) mfma_layer<32, 64, 40, 72>(bufA, bufB, sw1, b1, wave, lane);
    __syncthreads();
    if (tid < 256) mfma_layer<64, 128, 72, 136>(bufB, bufA, sw2, b2, wave, lane);
    __syncthreads();
    if (tid < 256) mfma_layer<128, 256, 136, 264>(bufA, bufB, sw3, b3, wave, lane);
    __syncthreads();
    if (tid < 256) mfma_layer4(bufB, sw4, b4, maxv, wave, lane);
    __syncthreads();
    if (tid < 240) {
      int jj = tid >> 2, q = tid & 3;
      const float* w = wpt + (size_t)jj * 512 + q * 128;
      float s = 0.f;
#pragma unroll 4
      for (int k = 0; k < 128; ++k) s = fmaf(maxv[q * 128 + k], w[k], s);
      psum[tid] = s;
    }
    __syncthreads();
    if (tid < kE) {
      float e = __fadd_rn(__fadd_rn(psum[tid * 4 + 0], psum[tid * 4 + 1]),
                          __fadd_rn(psum[tid * 4 + 2], psum[tid * 4 + 3])) + bp[tid];
      outE[((size_t)b * kG + it) * kE + tid] = e;
    }
    __syncthreads();  // smem reuse fence before next job
  }
}

// =====================  launch  =====================
extern "C" void kernel_launch(void* const* d_in, const int* in_sizes, int n_in,
                              void* d_out, int out_size, void* d_ws, size_t ws_size,
                              hipStream_t stream) {
  (void)in_sizes; (void)n_in; (void)out_size; (void)ws_size;
  const float* xyz = (const float*)d_in[0];
  const float* color = (const float*)d_in[1];
  const float* W1 = (const float*)d_in[2];
  const float* b1 = (const float*)d_in[3];
  const float* W2 = (const float*)d_in[4];
  const float* b2 = (const float*)d_in[5];
  const float* W3 = (const float*)d_in[6];
  const float* b3 = (const float*)d_in[7];
  const float* W4 = (const float*)d_in[8];
  const float* b4 = (const float*)d_in[9];
  const float* Wp = (const float*)d_in[10];
  const float* bp = (const float*)d_in[11];

  char* ws = (char*)d_ws;
  auto cline = (u64*)(ws + OFF_CLINE);
  auto ccnt = (uint32_t*)(ws + OFF_CCNT);
  auto gs = (uint32_t*)(ws + OFF_GS);
  auto cstart = (uint32_t*)(ws + OFF_CSTART);
  auto cur = (uint32_t*)(ws + OFF_CUR);
  auto dd = (float*)(ws + OFF_DD);
  auto sw1 = (_Float16*)(ws + OFF_SW1);
  auto sw2 = (_Float16*)(ws + OFF_SW2);
  auto sw3 = (_Float16*)(ws + OFF_SW3);
  auto sw4 = (_Float16*)(ws + OFF_SW4);
  auto wpt = (float*)(ws + OFF_WPT);
  auto sorted = (float4*)(ws + OFF_SORT);

  float* outE = (float*)d_out;
  float* outC = outE + (size_t)kB * kG * kE;

  k_zero<<<256, 256, 0, stream>>>((uint32_t*)ws, (int)(ZERO_BYTES / 4));
  k_prep<<<256, 256, 0, stream>>>(W1, W2, W3, W4, Wp, sw1, sw2, sw3, sw4, wpt);
  k_fused<<<NBLK, TPB, 0, stream>>>(xyz, color, outC, outE, cline, ccnt, cstart,
                                    cur, sorted, dd, gs, sw1, sw2, sw3, sw4, wpt,
                                    b1, b2, b3, b4, bp);
}